// Round 9
// baseline (237.793 us; speedup 1.0000x reference)
//
#include <hip/hip_runtime.h>
#include <math.h>

#define NSL 0.2f
#define BSH 8              // 256 nodes per bucket
#define CAP 4608           // edge capacity per bucket (mean 4092 @ E=1.6M,N=100K; +8 sigma)
#define ECHUNK 4096        // edges per block in pass A
#define MAXNB 512
// NOTE: src packed into 17 bits -> requires N <= 131072 (here N=100000)

typedef __attribute__((ext_vector_type(8))) short bf16x8;
typedef __attribute__((ext_vector_type(4))) float f32x4;
typedef __attribute__((ext_vector_type(2))) float floatx2;

__device__ __forceinline__ unsigned short f2b(float f){
  unsigned int u = __builtin_bit_cast(unsigned int, f);
  u = (u + 0x7FFFu + ((u >> 16) & 1u)) >> 16;   // RNE
  return (unsigned short)u;
}
__device__ __forceinline__ unsigned cvtpk_bf16(float a, float b){
  unsigned r; asm("v_cvt_pk_bf16_f32 %0, %1, %2" : "=v"(r) : "v"(a), "v"(b)); return r;
}
__device__ __forceinline__ void pkfma(floatx2& a, floatx2 x, floatx2 w){
  asm("v_pk_fma_f32 %0, %1, %2, %0" : "+v"(a) : "v"(x), "v"(w));
}

// ---------------- prep: W1 transpose->bf16 + gCur init (fused, saves a launch) ----------------
__global__ __launch_bounds__(256) void k_prep(const float* __restrict__ W, unsigned short* __restrict__ wt,
                                              int* gCur, int NB){
  int idx = blockIdx.x*256 + threadIdx.x;     // 32768 total
  int k = idx >> 8, ch = idx & 255;
  wt[ch*128 + k] = f2b(W[idx]);
  if (idx < NB) gCur[idx] = idx*CAP;
}

// Pass A: partition edges into per-bucket regions of ebuf; entry = src | (dst&255)<<17
__global__ __launch_bounds__(256) void k_bucket(const int* __restrict__ esrc, const int* __restrict__ edst,
                                                int E, int NB, int* gCur, unsigned* __restrict__ ebuf){
  __shared__ int hist[MAXNB];
  __shared__ int base[MAXNB];
  int t = threadIdx.x;
  for (int i=t;i<NB;i+=256) hist[i] = 0;
  __syncthreads();
  int e0 = blockIdx.x*ECHUNK;
  int srcv[16], dstv[16];
  #pragma unroll
  for (int j=0;j<16;j++){
    int e = e0 + t + j*256;
    if (e < E){ srcv[j] = esrc[e]; dstv[j] = edst[e]; atomicAdd(&hist[dstv[j]>>BSH], 1); }
    else dstv[j] = -1;
  }
  __syncthreads();
  for (int i=t;i<NB;i+=256){
    int h = hist[i];
    base[i] = h > 0 ? atomicAdd(&gCur[i], h) : 0;
    hist[i] = 0;
  }
  __syncthreads();
  #pragma unroll
  for (int j=0;j<16;j++){
    if (dstv[j] >= 0){
      int b = dstv[j]>>BSH;
      int pos = base[b] + atomicAdd(&hist[b], 1);
      if (pos < (b+1)*CAP)                 // overflow guard (never hit for this dist)
        ebuf[pos] = (unsigned)srcv[j] | ((unsigned)(dstv[j] & 255) << 17);
    }
  }
}

// Pass B: per-bucket local CSR in LDS + edge-record epilogue. Self loop at slot 0.
// rec[slot] = { src, bf16(w0,w1), bf16(w2,w3), 0 }, w_h = exp(leaky(asrc[src][h]+adst[dst][h])).
__global__ __launch_bounds__(256) void k_csr(const int* __restrict__ gCur, const unsigned* __restrict__ ebuf,
                                             const float* __restrict__ as4, const float* __restrict__ ad4,
                                             int* __restrict__ rows, int* __restrict__ deg,
                                             int* __restrict__ csr, uint4* __restrict__ rec, int N){
  __shared__ int lcnt[256];
  __shared__ int rofs[256];
  __shared__ int csr_l[CAP+256];
  __shared__ unsigned char dl_l[CAP+256];
  int b = blockIdx.x, t = threadIdx.x;
  int node0 = b<<BSH;
  int nNodes = min(256, N - node0);
  int cnt_b = min(gCur[b] - b*CAP, CAP);
  lcnt[t] = 0;
  __syncthreads();
  const unsigned* eb = ebuf + (size_t)b*CAP;
  for (int i=t;i<cnt_b;i+=256) atomicAdd(&lcnt[eb[i]>>17], 1);
  __syncthreads();
  int v = (t < nNodes) ? (lcnt[t] + 1) : 0;   // +1: self loop
  rofs[t] = v; __syncthreads();
  #pragma unroll
  for (int o=1;o<256;o<<=1){
    int x = (t>=o) ? rofs[t-o] : 0; __syncthreads();
    rofs[t] += x; __syncthreads();
  }
  int excl = rofs[t] - v;
  if (t < nNodes){ csr_l[excl] = node0 + t; dl_l[excl] = (unsigned char)t; }  // self loop
  lcnt[t] = excl + 1;                         // fill cursor
  __syncthreads();
  for (int i=t;i<cnt_b;i+=256){
    unsigned e = eb[i];
    int dl = e >> 17;
    int pos = atomicAdd(&lcnt[dl], 1);
    csr_l[pos] = (int)(e & 0x1FFFFu);
    dl_l[pos]  = (unsigned char)dl;
  }
  __syncthreads();
  int total = rofs[255];
  int gbase = b*(CAP+256);
  for (int i=t;i<total;i+=256){
    int src = csr_l[i];
    int dl  = dl_l[i];
    float4 av = *(const float4*)&as4[(size_t)src*4];
    float4 dv = *(const float4*)&ad4[(size_t)(node0+dl)*4];
    float ax = av.x+dv.x, ay = av.y+dv.y, az = av.z+dv.z, aw = av.w+dv.w;
    ax = fmaxf(ax, NSL*ax); ay = fmaxf(ay, NSL*ay);
    az = fmaxf(az, NSL*az); aw = fmaxf(aw, NSL*aw);
    uint4 r;
    r.x = (unsigned)src;
    r.y = cvtpk_bf16(__expf(ax), __expf(ay));
    r.z = cvtpk_bf16(__expf(az), __expf(aw));
    r.w = 0u;
    rec[gbase+i] = r;
    csr[gbase+i] = src;
  }
  // zero-pad 16 records past the bucket's data (enables unconditional loads in agg1)
  if (t < 16){
    int p = total + t;
    if (p < CAP+256) rec[gbase+p] = (uint4){0u,0u,0u,0u};
  }
  if (t < nNodes){ rows[node0+t] = gbase + excl; deg[node0+t] = v; }
}

// ---------------- MFMA GEMM: block = 64 nodes x 256 ch, wave = head ----------------
__global__ __launch_bounds__(256) void k_gemm1(const unsigned short* __restrict__ w1t,
                                               const float* __restrict__ x,
                                               const float* __restrict__ a_s1,
                                               const float* __restrict__ a_d1,
                                               unsigned char* __restrict__ h1f8,
                                               float* __restrict__ asrc, float* __restrict__ adst,
                                               int N){
  __shared__ unsigned short xs[64][132];      // 132-stride: bank-spread for ds_read_b64
  int tid = threadIdx.x;
  int lane = tid & 63, w = tid >> 6;          // w = head
  int g = lane >> 4, nr = lane & 15;
  int n0 = blockIdx.x*64;

  #pragma unroll
  for (int i=0;i<8;i++){
    int idx = tid + i*256;
    int node = idx >> 5, c4 = idx & 31;
    int gn = n0 + node;
    float4 v = (gn < N) ? *(const float4*)&x[(size_t)gn*128 + c4*4] : make_float4(0,0,0,0);
    uint2 pk = { cvtpk_bf16(v.x, v.y), cvtpk_bf16(v.z, v.w) };
    *(uint2*)&xs[node][c4*4] = pk;
  }
  __syncthreads();

  int node_f[4]; bool val_f[4];
  #pragma unroll
  for (int fn=0;fn<4;fn++){ node_f[fn] = n0 + fn*16 + nr; val_f[fn] = node_f[fn] < N; }

  f32x4 acc[4][4] = {};
  #pragma unroll
  for (int s=0;s<4;s++){
    int ks = s*32;
    bf16x8 af[4], bf[4];
    #pragma unroll
    for (int fm=0;fm<4;fm++){
      int ch = w*64 + fm*16 + nr;
      const ushort4 lo = *(const ushort4*)(w1t + ch*128 + ks + 4*g);
      const ushort4 hi = *(const ushort4*)(w1t + ch*128 + ks + 16 + 4*g);
      af[fm] = (bf16x8){ (short)lo.x,(short)lo.y,(short)lo.z,(short)lo.w,
                         (short)hi.x,(short)hi.y,(short)hi.z,(short)hi.w };
    }
    #pragma unroll
    for (int fn=0;fn<4;fn++){
      union { uint2 u2[2]; bf16x8 v; } bb;
      bb.u2[0] = *(const uint2*)&xs[fn*16 + nr][ks + 4*g];
      bb.u2[1] = *(const uint2*)&xs[fn*16 + nr][ks + 16 + 4*g];
      bf[fn] = bb.v;
    }
    #pragma unroll
    for (int fm=0;fm<4;fm++)
      #pragma unroll
      for (int fn=0;fn<4;fn++)
        acc[fm][fn] = __builtin_amdgcn_mfma_f32_16x16x32_bf16(af[fm], bf[fn], acc[fm][fn], 0, 0, 0);
  }

  float ps[4] = {0.f,0.f,0.f,0.f}, pd[4] = {0.f,0.f,0.f,0.f};
  #pragma unroll
  for (int fm=0;fm<4;fm++){
    int cb = w*64 + fm*16 + g*4;
    float4 av = *(const float4*)&a_s1[cb];
    float4 dv = *(const float4*)&a_d1[cb];
    #pragma unroll
    for (int fn=0;fn<4;fn++){
      f32x4 c = acc[fm][fn];
      if (val_f[fn]){
        int u = __builtin_amdgcn_cvt_pk_fp8_f32(c[0], c[1], 0, false);
        u = __builtin_amdgcn_cvt_pk_fp8_f32(c[2], c[3], u, true);
        *(unsigned int*)(h1f8 + (size_t)node_f[fn]*256 + cb) = (unsigned int)u;
      }
      ps[fn] += c[0]*av.x + c[1]*av.y + c[2]*av.z + c[3]*av.w;
      pd[fn] += c[0]*dv.x + c[1]*dv.y + c[2]*dv.z + c[3]*dv.w;
    }
  }
  #pragma unroll
  for (int fn=0;fn<4;fn++){
    ps[fn] += __shfl_xor(ps[fn], 16); ps[fn] += __shfl_xor(ps[fn], 32);
    pd[fn] += __shfl_xor(pd[fn], 16); pd[fn] += __shfl_xor(pd[fn], 32);
    if (g == 0 && val_f[fn]){
      asrc[node_f[fn]*4 + w] = ps[fn];
      adst[node_f[fn]*4 + w] = pd[fn];
    }
  }
}

// ---------------- layer-1 aggregation: single-record loads, SSA ping-pong, maskless streams ----------------
__global__ __launch_bounds__(256) void k_agg1(const int* __restrict__ rows, const int* __restrict__ deg,
                                              const uint4* __restrict__ rec,
                                              const unsigned char* __restrict__ h1f8,
                                              const float* __restrict__ b1,
                                              const float* __restrict__ gamma, const float* __restrict__ beta,
                                              const float* __restrict__ W2,
                                              float* __restrict__ h2, int N){
  int lane = threadIdx.x & 63, wv = threadIdx.x >> 6;
  int node = blockIdx.x*4 + wv;
  if (node >= N) return;
  int slot = lane >> 4, l4 = lane & 15;   // slot: edge phase (4); l4: 16 channels
  int head = l4 >> 2;
  bool h23 = head >= 2;
  bool hhi = (head & 1) != 0;
  int rs = rows[node], d = deg[node];
  int dms = d - slot;                      // edge live iff 4*t < dms
  const uint4* recp = rec + rs;
  const uint4* h1u4 = (const uint4*)h1f8;  // one row = 16 uint4
  floatx2 acc2[8];
  #pragma unroll
  for (int j=0;j<8;j++){ acc2[j][0] = 0.f; acc2[j][1] = 0.f; }
  float den = 0.f;
  int nj = (d + 3) >> 2;

  auto step = [&](const uint4& r, const uint4& v, int t4){
    unsigned ws = h23 ? r.z : r.y;
    unsigned hw = hhi ? (ws & 0xFFFF0000u) : (ws << 16);
    float w = __builtin_bit_cast(float, hw);
    w = (t4 < dms) ? w : 0.f;
    den += w;
    floatx2 ww; ww[0] = w; ww[1] = w;
    floatx2 f;
    f = __builtin_amdgcn_cvt_pk_f32_fp8(v.x, false); pkfma(acc2[0], f, ww);
    f = __builtin_amdgcn_cvt_pk_f32_fp8(v.x, true ); pkfma(acc2[1], f, ww);
    f = __builtin_amdgcn_cvt_pk_f32_fp8(v.y, false); pkfma(acc2[2], f, ww);
    f = __builtin_amdgcn_cvt_pk_f32_fp8(v.y, true ); pkfma(acc2[3], f, ww);
    f = __builtin_amdgcn_cvt_pk_f32_fp8(v.z, false); pkfma(acc2[4], f, ww);
    f = __builtin_amdgcn_cvt_pk_f32_fp8(v.z, true ); pkfma(acc2[5], f, ww);
    f = __builtin_amdgcn_cvt_pk_f32_fp8(v.w, false); pkfma(acc2[6], f, ww);
    f = __builtin_amdgcn_cvt_pk_f32_fp8(v.w, true ); pkfma(acc2[7], f, ww);
  };

  // prologue (unconditional: bucket tails are zero-padded, mid-bucket spill reads
  // neighbor records whose weights get masked by t4 < dms)
  uint4 rA = recp[slot];
  uint4 rB = recp[slot + 4];
  uint4 vA = h1u4[(size_t)rA.x*16 + l4];
  uint4 vB = h1u4[(size_t)rB.x*16 + l4];

  int t = 0;
  for (; t + 2 <= nj; t += 2){
    uint4 rA2 = recp[slot + 4*t + 8];
    step(rA, vA, 4*t);
    vA = h1u4[(size_t)rA2.x*16 + l4];
    rA = rA2;
    uint4 rB2 = recp[slot + 4*t + 12];
    step(rB, vB, 4*t + 4);
    vB = h1u4[(size_t)rB2.x*16 + l4];
    rB = rB2;
  }
  if (t < nj) step(rA, vA, 4*t);

  #pragma unroll
  for (int j=0;j<8;j++){
    acc2[j][0] += __shfl_xor(acc2[j][0],16); acc2[j][1] += __shfl_xor(acc2[j][1],16);
    acc2[j][0] += __shfl_xor(acc2[j][0],32); acc2[j][1] += __shfl_xor(acc2[j][1],32);
  }
  den += __shfl_xor(den,16); den += __shfl_xor(den,32);
  float inv = 1.f/den;
  const float bsc = 0.99999500003749968f;  // 1/sqrt(1+1e-5)
  int c = l4*16;
  float p = 0.f;
  #pragma unroll
  for (int q=0;q<4;q++){
    int cq = c + q*4;
    float4 bb = *(const float4*)&b1[cq];
    float4 gg = *(const float4*)&gamma[cq];
    float4 be = *(const float4*)&beta[cq];
    float4 w2_ = *(const float4*)&W2[cq];
    float o0 = (acc2[q*2+0][0]*inv + bb.x)*bsc*gg.x + be.x;
    float o1 = (acc2[q*2+0][1]*inv + bb.y)*bsc*gg.y + be.y;
    float o2 = (acc2[q*2+1][0]*inv + bb.z)*bsc*gg.z + be.z;
    float o3 = (acc2[q*2+1][1]*inv + bb.w)*bsc*gg.w + be.w;
    o0 = (o0>0.f)?o0:(__expf(o0)-1.f); o1 = (o1>0.f)?o1:(__expf(o1)-1.f);
    o2 = (o2>0.f)?o2:(__expf(o2)-1.f); o3 = (o3>0.f)?o3:(__expf(o3)-1.f);
    p += o0*w2_.x + o1*w2_.y + o2*w2_.z + o3*w2_.w;
  }
  p += __shfl_xor(p,1); p += __shfl_xor(p,2); p += __shfl_xor(p,4); p += __shfl_xor(p,8);
  if (lane == 0) h2[node] = p;
}

// ---------------- layer-2 aggregation + MLP + sigmoid: 16 lanes per node ----------------
__global__ __launch_bounds__(256) void k_agg2(const int* __restrict__ rows, const int* __restrict__ deg,
                       const int* __restrict__ csr, const float* __restrict__ h2,
                       const float* __restrict__ as2, const float* __restrict__ ad2,
                       const float* __restrict__ b2,
                       const float* __restrict__ mw1, const float* __restrict__ mb1,
                       const float* __restrict__ mw2, const float* __restrict__ mb2,
                       float* __restrict__ out, int N){
  int t = threadIdx.x;
  int g16 = t >> 4, l = t & 15;
  int n = blockIdx.x*16 + g16;
  if (n >= N) return;
  float a_s = as2[0], a_d = ad2[0];
  float hd = h2[n];
  float ad = hd * a_d;
  int rs = rows[n], d = deg[n];
  float den = 0.f, num = 0.f;
  for (int i=l;i<d;i+=16){
    int s = csr[rs+i];
    float hs = h2[s];
    float al = hs*a_s + ad;
    al = fmaxf(al, NSL*al);
    float w = __expf(al);
    den += w; num += w*hs;
  }
  #pragma unroll
  for (int o=1;o<16;o<<=1){ den += __shfl_xor(den,o); num += __shfl_xor(num,o); }
  float o2 = num/den + b2[0];
  float acc = 0.f;
  #pragma unroll
  for (int q=0;q<4;q++){
    int j = l + q*16;
    float r = fmaxf(o2*mw1[j] + mb1[j], 0.f);
    acc += r*mw2[j];
  }
  #pragma unroll
  for (int o=1;o<16;o<<=1) acc += __shfl_xor(acc,o);
  if (l == 0) out[n] = 1.f/(1.f + __expf(-(acc + mb2[0])));
}

extern "C" void kernel_launch(void* const* d_in, const int* in_sizes, int n_in,
                              void* d_out, int out_size, void* d_ws, size_t ws_size,
                              hipStream_t stream){
  const float* x   = (const float*)d_in[0];
  const int*   ei  = (const int*)  d_in[1];
  const float* W1  = (const float*)d_in[2];
  const float* as1 = (const float*)d_in[3];
  const float* ad1 = (const float*)d_in[4];
  const float* b1  = (const float*)d_in[5];
  const float* gam = (const float*)d_in[6];
  const float* bet = (const float*)d_in[7];
  const float* W2  = (const float*)d_in[8];
  const float* as2 = (const float*)d_in[9];
  const float* ad2 = (const float*)d_in[10];
  const float* b2  = (const float*)d_in[11];
  const float* mw1 = (const float*)d_in[12];
  const float* mb1 = (const float*)d_in[13];
  const float* mw2 = (const float*)d_in[14];
  const float* mb2 = (const float*)d_in[15];
  float* out = (float*)d_out;

  int N = in_sizes[0] / 128;
  int E = in_sizes[1] / 2;
  const int* esrc = ei;
  const int* edst = ei + E;
  int NB = (N + 255) >> 8;

  char* p = (char*)d_ws;
  auto alloc = [&](size_t bytes)->char*{ char* r = p; p += (bytes + 255) & ~(size_t)255; return r; };
  int*      deg   = (int*)     alloc((size_t)N*4);
  int*      rows  = (int*)     alloc((size_t)N*4);
  int*      gCur  = (int*)     alloc((size_t)NB*4);
  unsigned* ebuf  = (unsigned*)alloc((size_t)NB*CAP*4);
  int*      csr   = (int*)     alloc((size_t)NB*(CAP+256)*4);
  uint4*    rec   = (uint4*)   alloc((size_t)NB*(CAP+256)*16 + 256);
  unsigned short* w1t  = (unsigned short*)alloc((size_t)256*128*2);
  unsigned char*  h1f8 = (unsigned char*) alloc((size_t)N*256);
  float* asrc  = (float*)alloc((size_t)N*4*4);
  float* adst  = (float*)alloc((size_t)N*4*4);
  float* h2    = (float*)alloc((size_t)N*4);

  k_prep<<<128,256,0,stream>>>(W1, w1t, gCur, NB);
  int nbA = (E + ECHUNK - 1)/ECHUNK;
  k_bucket<<<nbA,256,0,stream>>>(esrc, edst, E, NB, gCur, ebuf);

  k_gemm1<<<(N+63)/64,256,0,stream>>>(w1t, x, as1, ad1, h1f8, asrc, adst, N);

  // csr build consumes gemm1's alpha outputs to emit per-edge records {src, bf16 weights}
  k_csr<<<NB,256,0,stream>>>(gCur, ebuf, asrc, adst, rows, deg, csr, rec, N);

  k_agg1<<<(N+3)/4,256,0,stream>>>(rows, deg, rec, h1f8, b1, gam, bet, W2, h2, N);

  k_agg2<<<(N+15)/16,256,0,stream>>>(rows, deg, csr, h2, as2, ad2, b2, mw1, mb1, mw2, mb2, out, N);
}

// Round 10
// 217.202 us; speedup vs baseline: 1.0948x; 1.0948x over previous
//
#include <hip/hip_runtime.h>
#include <math.h>

#define NSL 0.2f
#define BSH 8              // 256 nodes per bucket
#define CAP 4608           // edge capacity per bucket (mean 4092 @ E=1.6M,N=100K; +8 sigma)
#define ECHUNK 4096        // edges per block in bucket pass
#define MAXNB 512
// NOTE: src packed into 17 bits -> requires N <= 131072 (here N=100000)

typedef __attribute__((ext_vector_type(8))) short bf16x8;
typedef __attribute__((ext_vector_type(4))) float f32x4;
typedef __attribute__((ext_vector_type(2))) float floatx2;

__device__ __forceinline__ unsigned short f2b(float f){
  unsigned int u = __builtin_bit_cast(unsigned int, f);
  u = (u + 0x7FFFu + ((u >> 16) & 1u)) >> 16;   // RNE
  return (unsigned short)u;
}
__device__ __forceinline__ unsigned cvtpk_bf16(float a, float b){
  unsigned r; asm("v_cvt_pk_bf16_f32 %0, %1, %2" : "=v"(r) : "v"(a), "v"(b)); return r;
}
__device__ __forceinline__ void pkfma(floatx2& a, floatx2 x, floatx2 w){
  asm("v_pk_fma_f32 %0, %1, %2, %0" : "+v"(a) : "v"(x), "v"(w));
}

// ---------------- fused 1: W1 transpose->bf16 (blocks [0,prepBlocks)) ∥ edge bucketing ----------------
// gCur starts 0 (hipMemsetAsync); holds per-bucket edge COUNT.
__global__ __launch_bounds__(256) void k_fused1(const float* __restrict__ W, unsigned short* __restrict__ wt,
                                                const int* __restrict__ esrc, const int* __restrict__ edst,
                                                int E, int NB, int* gCur, unsigned* __restrict__ ebuf,
                                                int prepBlocks){
  __shared__ int hist[MAXNB];
  __shared__ int base[MAXNB];
  int bid = blockIdx.x, t = threadIdx.x;
  if (bid < prepBlocks){
    int idx = bid*256 + t;                 // 32768 total
    int k = idx >> 8, ch = idx & 255;
    wt[ch*128 + k] = f2b(W[idx]);
    return;
  }
  int b0 = bid - prepBlocks;
  for (int i=t;i<NB;i+=256) hist[i] = 0;
  __syncthreads();
  int e0 = b0*ECHUNK;
  int srcv[16], dstv[16];
  #pragma unroll
  for (int j=0;j<16;j++){
    int e = e0 + t + j*256;
    if (e < E){ srcv[j] = esrc[e]; dstv[j] = edst[e]; atomicAdd(&hist[dstv[j]>>BSH], 1); }
    else dstv[j] = -1;
  }
  __syncthreads();
  for (int i=t;i<NB;i+=256){
    int h = hist[i];
    base[i] = h > 0 ? atomicAdd(&gCur[i], h) : 0;
    hist[i] = 0;
  }
  __syncthreads();
  #pragma unroll
  for (int j=0;j<16;j++){
    if (dstv[j] >= 0){
      int b = dstv[j]>>BSH;
      int pos = base[b] + atomicAdd(&hist[b], 1);
      if (pos < CAP)                       // overflow guard (never hit for this dist)
        ebuf[(size_t)b*CAP + pos] = (unsigned)srcv[j] | ((unsigned)(dstv[j] & 255) << 17);
    }
  }
}

// ---------------- fused 2: MFMA GEMM (blocks [0,gemmBlocks)) ∥ per-bucket CSR build ----------------
__global__ __launch_bounds__(256) void k_fused2(const unsigned short* __restrict__ w1t,
                                                const float* __restrict__ x,
                                                const float* __restrict__ a_s1,
                                                const float* __restrict__ a_d1,
                                                unsigned char* __restrict__ h1f8,
                                                float* __restrict__ asrc, float* __restrict__ adst,
                                                int N, int gemmBlocks,
                                                const int* __restrict__ gCur, const unsigned* __restrict__ ebuf,
                                                int* __restrict__ rows, int* __restrict__ deg,
                                                int* __restrict__ csr){
  __shared__ union SM {
    unsigned short xs[64][132];                          // gemm: 16.9 KB (132-stride bank spread)
    struct { int lcnt[256]; int rofs[256]; int csr_l[CAP+256]; } c;   // csr: 21.5 KB
  } sm;
  int tid = threadIdx.x;
  int bid = blockIdx.x;

  if (bid < gemmBlocks){
    // ---- GEMM: block = 64 nodes x 256 ch, wave = head ----
    int lane = tid & 63, w = tid >> 6;
    int g = lane >> 4, nr = lane & 15;
    int n0 = bid*64;
    #pragma unroll
    for (int i=0;i<8;i++){
      int idx = tid + i*256;
      int node = idx >> 5, c4 = idx & 31;
      int gn = n0 + node;
      float4 v = (gn < N) ? *(const float4*)&x[(size_t)gn*128 + c4*4] : make_float4(0,0,0,0);
      uint2 pk = { cvtpk_bf16(v.x, v.y), cvtpk_bf16(v.z, v.w) };
      *(uint2*)&sm.xs[node][c4*4] = pk;
    }
    __syncthreads();

    int node_f[4]; bool val_f[4];
    #pragma unroll
    for (int fn=0;fn<4;fn++){ node_f[fn] = n0 + fn*16 + nr; val_f[fn] = node_f[fn] < N; }

    f32x4 acc[4][4] = {};
    #pragma unroll
    for (int s=0;s<4;s++){
      int ks = s*32;
      bf16x8 af[4], bf[4];
      #pragma unroll
      for (int fm=0;fm<4;fm++){
        int ch = w*64 + fm*16 + nr;
        const ushort4 lo = *(const ushort4*)(w1t + ch*128 + ks + 4*g);
        const ushort4 hi = *(const ushort4*)(w1t + ch*128 + ks + 16 + 4*g);
        af[fm] = (bf16x8){ (short)lo.x,(short)lo.y,(short)lo.z,(short)lo.w,
                           (short)hi.x,(short)hi.y,(short)hi.z,(short)hi.w };
      }
      #pragma unroll
      for (int fn=0;fn<4;fn++){
        union { uint2 u2[2]; bf16x8 v; } bb;
        bb.u2[0] = *(const uint2*)&sm.xs[fn*16 + nr][ks + 4*g];
        bb.u2[1] = *(const uint2*)&sm.xs[fn*16 + nr][ks + 16 + 4*g];
        bf[fn] = bb.v;
      }
      #pragma unroll
      for (int fm=0;fm<4;fm++)
        #pragma unroll
        for (int fn=0;fn<4;fn++)
          acc[fm][fn] = __builtin_amdgcn_mfma_f32_16x16x32_bf16(af[fm], bf[fn], acc[fm][fn], 0, 0, 0);
    }

    float ps[4] = {0.f,0.f,0.f,0.f}, pd[4] = {0.f,0.f,0.f,0.f};
    #pragma unroll
    for (int fm=0;fm<4;fm++){
      int cb = w*64 + fm*16 + g*4;
      float4 av = *(const float4*)&a_s1[cb];
      float4 dv = *(const float4*)&a_d1[cb];
      #pragma unroll
      for (int fn=0;fn<4;fn++){
        f32x4 c = acc[fm][fn];
        if (val_f[fn]){
          int u = __builtin_amdgcn_cvt_pk_fp8_f32(c[0], c[1], 0, false);
          u = __builtin_amdgcn_cvt_pk_fp8_f32(c[2], c[3], u, true);
          *(unsigned int*)(h1f8 + (size_t)node_f[fn]*256 + cb) = (unsigned int)u;
        }
        ps[fn] += c[0]*av.x + c[1]*av.y + c[2]*av.z + c[3]*av.w;
        pd[fn] += c[0]*dv.x + c[1]*dv.y + c[2]*dv.z + c[3]*dv.w;
      }
    }
    #pragma unroll
    for (int fn=0;fn<4;fn++){
      ps[fn] += __shfl_xor(ps[fn], 16); ps[fn] += __shfl_xor(ps[fn], 32);
      pd[fn] += __shfl_xor(pd[fn], 16); pd[fn] += __shfl_xor(pd[fn], 32);
      if (g == 0 && val_f[fn]){
        asrc[node_f[fn]*4 + w] = ps[fn];
        adst[node_f[fn]*4 + w] = pd[fn];
      }
    }
  } else {
    // ---- CSR build: per-bucket local CSR in LDS, coalesced write-out. Self loop at slot 0. ----
    int b = bid - gemmBlocks;
    int node0 = b<<BSH;
    int nNodes = min(256, N - node0);
    int cnt_b = min(gCur[b], CAP);
    sm.c.lcnt[tid] = 0;
    __syncthreads();
    const unsigned* eb = ebuf + (size_t)b*CAP;
    for (int i=tid;i<cnt_b;i+=256) atomicAdd(&sm.c.lcnt[eb[i]>>17], 1);
    __syncthreads();
    int v = (tid < nNodes) ? (sm.c.lcnt[tid] + 1) : 0;   // +1: self loop
    sm.c.rofs[tid] = v; __syncthreads();
    #pragma unroll
    for (int o=1;o<256;o<<=1){
      int xv = (tid>=o) ? sm.c.rofs[tid-o] : 0; __syncthreads();
      sm.c.rofs[tid] += xv; __syncthreads();
    }
    int excl = sm.c.rofs[tid] - v;
    if (tid < nNodes) sm.c.csr_l[excl] = node0 + tid;    // self loop
    sm.c.lcnt[tid] = excl + 1;                           // fill cursor
    __syncthreads();
    for (int i=tid;i<cnt_b;i+=256){
      unsigned e = eb[i];
      int pos = atomicAdd(&sm.c.lcnt[e>>17], 1);
      sm.c.csr_l[pos] = (int)(e & 0x1FFFFu);
    }
    __syncthreads();
    int total = sm.c.rofs[255];
    int gbase = b*(CAP+256);
    for (int i=tid;i<total;i+=256) csr[gbase+i] = sm.c.csr_l[i];
    if (tid < nNodes){ rows[node0+tid] = gbase + excl; deg[node0+tid] = v; }
  }
}

// ---------------- layer-1 aggregation (r6 form, proven 129.6us): 4 edges in flight, inline weights ----------------
__global__ __launch_bounds__(256) void k_agg1(const int* __restrict__ rows, const int* __restrict__ deg,
                                              const int* __restrict__ csr,
                                              const unsigned char* __restrict__ h1f8,
                                              const float* __restrict__ asrc, const float* __restrict__ adst,
                                              const float* __restrict__ b1,
                                              const float* __restrict__ gamma, const float* __restrict__ beta,
                                              const float* __restrict__ W2,
                                              float* __restrict__ h2, int N){
  int lane = threadIdx.x & 63, wv = threadIdx.x >> 6;
  int node = blockIdx.x*4 + wv;
  if (node >= N) return;
  int slot = lane >> 4, l4 = lane & 15;   // slot: edge phase (4); l4: 16 channels
  int head = l4 >> 2;
  int rs = rows[node], d = deg[node];
  float adh = adst[node*4 + head];
  const uint4* h1u4 = (const uint4*)h1f8;  // one row = 16 uint4
  floatx2 acc2[8];
  #pragma unroll
  for (int j=0;j<8;j++){ acc2[j][0] = 0.f; acc2[j][1] = 0.f; }
  float den = 0.f;
  int i = slot;
  if (i < d){
    int s = csr[rs+i];
    float aa = asrc[s*4 + head];
    uint4 v = h1u4[(size_t)s*16 + l4];
    while (true){
      int in = i + 4;
      bool hn = in < d;
      int sn = hn ? csr[rs+in] : 0;
      float al = aa + adh;
      al = fmaxf(al, NSL*al);              // leaky_relu
      float wgt = __expf(al);              // no max-subtraction: |al| small
      den += wgt;
      floatx2 ww; ww[0] = wgt; ww[1] = wgt;
      floatx2 f;
      f = __builtin_amdgcn_cvt_pk_f32_fp8(v.x, false); pkfma(acc2[0], f, ww);
      f = __builtin_amdgcn_cvt_pk_f32_fp8(v.x, true ); pkfma(acc2[1], f, ww);
      f = __builtin_amdgcn_cvt_pk_f32_fp8(v.y, false); pkfma(acc2[2], f, ww);
      f = __builtin_amdgcn_cvt_pk_f32_fp8(v.y, true ); pkfma(acc2[3], f, ww);
      f = __builtin_amdgcn_cvt_pk_f32_fp8(v.z, false); pkfma(acc2[4], f, ww);
      f = __builtin_amdgcn_cvt_pk_f32_fp8(v.z, true ); pkfma(acc2[5], f, ww);
      f = __builtin_amdgcn_cvt_pk_f32_fp8(v.w, false); pkfma(acc2[6], f, ww);
      f = __builtin_amdgcn_cvt_pk_f32_fp8(v.w, true ); pkfma(acc2[7], f, ww);
      if (!hn) break;
      i = in;
      aa = asrc[sn*4 + head];
      v = h1u4[(size_t)sn*16 + l4];
    }
  }
  #pragma unroll
  for (int j=0;j<8;j++){
    acc2[j][0] += __shfl_xor(acc2[j][0],16); acc2[j][1] += __shfl_xor(acc2[j][1],16);
    acc2[j][0] += __shfl_xor(acc2[j][0],32); acc2[j][1] += __shfl_xor(acc2[j][1],32);
  }
  den += __shfl_xor(den,16); den += __shfl_xor(den,32);
  float inv = 1.f/den;
  const float bsc = 0.99999500003749968f;  // 1/sqrt(1+1e-5)
  int c = l4*16;
  float p = 0.f;
  #pragma unroll
  for (int q=0;q<4;q++){
    int cq = c + q*4;
    float4 bb = *(const float4*)&b1[cq];
    float4 gg = *(const float4*)&gamma[cq];
    float4 be = *(const float4*)&beta[cq];
    float4 w2_ = *(const float4*)&W2[cq];
    float o0 = (acc2[q*2+0][0]*inv + bb.x)*bsc*gg.x + be.x;
    float o1 = (acc2[q*2+0][1]*inv + bb.y)*bsc*gg.y + be.y;
    float o2 = (acc2[q*2+1][0]*inv + bb.z)*bsc*gg.z + be.z;
    float o3 = (acc2[q*2+1][1]*inv + bb.w)*bsc*gg.w + be.w;
    o0 = (o0>0.f)?o0:(__expf(o0)-1.f); o1 = (o1>0.f)?o1:(__expf(o1)-1.f);
    o2 = (o2>0.f)?o2:(__expf(o2)-1.f); o3 = (o3>0.f)?o3:(__expf(o3)-1.f);
    p += o0*w2_.x + o1*w2_.y + o2*w2_.z + o3*w2_.w;
  }
  p += __shfl_xor(p,1); p += __shfl_xor(p,2); p += __shfl_xor(p,4); p += __shfl_xor(p,8);
  if (lane == 0) h2[node] = p;
}

// ---------------- layer-2 aggregation + MLP + sigmoid: 16 lanes per node ----------------
__global__ __launch_bounds__(256) void k_agg2(const int* __restrict__ rows, const int* __restrict__ deg,
                       const int* __restrict__ csr, const float* __restrict__ h2,
                       const float* __restrict__ as2, const float* __restrict__ ad2,
                       const float* __restrict__ b2,
                       const float* __restrict__ mw1, const float* __restrict__ mb1,
                       const float* __restrict__ mw2, const float* __restrict__ mb2,
                       float* __restrict__ out, int N){
  int t = threadIdx.x;
  int g16 = t >> 4, l = t & 15;
  int n = blockIdx.x*16 + g16;
  if (n >= N) return;
  float a_s = as2[0], a_d = ad2[0];
  float hd = h2[n];
  float ad = hd * a_d;
  int rs = rows[n], d = deg[n];
  float den = 0.f, num = 0.f;
  for (int i=l;i<d;i+=16){
    int s = csr[rs+i];
    float hs = h2[s];
    float al = hs*a_s + ad;
    al = fmaxf(al, NSL*al);
    float w = __expf(al);
    den += w; num += w*hs;
  }
  #pragma unroll
  for (int o=1;o<16;o<<=1){ den += __shfl_xor(den,o); num += __shfl_xor(num,o); }
  float o2 = num/den + b2[0];
  float acc = 0.f;
  #pragma unroll
  for (int q=0;q<4;q++){
    int j = l + q*16;
    float r = fmaxf(o2*mw1[j] + mb1[j], 0.f);
    acc += r*mw2[j];
  }
  #pragma unroll
  for (int o=1;o<16;o<<=1) acc += __shfl_xor(acc,o);
  if (l == 0) out[n] = 1.f/(1.f + __expf(-(acc + mb2[0])));
}

extern "C" void kernel_launch(void* const* d_in, const int* in_sizes, int n_in,
                              void* d_out, int out_size, void* d_ws, size_t ws_size,
                              hipStream_t stream){
  const float* x   = (const float*)d_in[0];
  const int*   ei  = (const int*)  d_in[1];
  const float* W1  = (const float*)d_in[2];
  const float* as1 = (const float*)d_in[3];
  const float* ad1 = (const float*)d_in[4];
  const float* b1  = (const float*)d_in[5];
  const float* gam = (const float*)d_in[6];
  const float* bet = (const float*)d_in[7];
  const float* W2  = (const float*)d_in[8];
  const float* as2 = (const float*)d_in[9];
  const float* ad2 = (const float*)d_in[10];
  const float* b2  = (const float*)d_in[11];
  const float* mw1 = (const float*)d_in[12];
  const float* mb1 = (const float*)d_in[13];
  const float* mw2 = (const float*)d_in[14];
  const float* mb2 = (const float*)d_in[15];
  float* out = (float*)d_out;

  int N = in_sizes[0] / 128;
  int E = in_sizes[1] / 2;
  const int* esrc = ei;
  const int* edst = ei + E;
  int NB = (N + 255) >> 8;

  char* p = (char*)d_ws;
  auto alloc = [&](size_t bytes)->char*{ char* r = p; p += (bytes + 255) & ~(size_t)255; return r; };
  int*      deg   = (int*)     alloc((size_t)N*4);
  int*      rows  = (int*)     alloc((size_t)N*4);
  int*      gCur  = (int*)     alloc((size_t)NB*4);
  unsigned* ebuf  = (unsigned*)alloc((size_t)NB*CAP*4);
  int*      csr   = (int*)     alloc((size_t)NB*(CAP+256)*4);
  unsigned short* w1t  = (unsigned short*)alloc((size_t)256*128*2);
  unsigned char*  h1f8 = (unsigned char*) alloc((size_t)N*256);
  float* asrc  = (float*)alloc((size_t)N*4*4);
  float* adst  = (float*)alloc((size_t)N*4*4);
  float* h2    = (float*)alloc((size_t)N*4);

  hipMemsetAsync(gCur, 0, (size_t)NB*4, stream);

  int prepBlocks = 128;
  int nbA = (E + ECHUNK - 1)/ECHUNK;
  k_fused1<<<prepBlocks + nbA, 256, 0, stream>>>(W1, w1t, esrc, edst, E, NB, gCur, ebuf, prepBlocks);

  int gemmBlocks = (N + 63)/64;
  k_fused2<<<gemmBlocks + NB, 256, 0, stream>>>(w1t, x, as1, ad1, h1f8, asrc, adst,
                                                N, gemmBlocks, gCur, ebuf, rows, deg, csr);

  k_agg1<<<(N+3)/4,256,0,stream>>>(rows, deg, csr, h1f8, asrc, adst, b1, gam, bet, W2, h2, N);

  k_agg2<<<(N+15)/16,256,0,stream>>>(rows, deg, csr, h2, as2, ad2, b2, mw1, mb1, mw2, mb2, out, N);
}